// Round 8
// baseline (211.377 us; speedup 1.0000x reference)
//
#include <hip/hip_runtime.h>
#include <math.h>

#define NRES 22

// R2 structure resurrected verbatim, ONE change: __launch_bounds__(256,2) ->
// plain __launch_bounds__(256). R2's 155us was pure scratch-spill (VGPR
// capped at 128, body needs ~150-170; FETCH 106MB / WRITE 270MB). Plain
// (256) is the only spelling that lets the allocator match the body's need
// (R0/R4/R7: 92/112/104, all spill-free). Expected: ~160 VGPR, 3 waves/SIMD,
// LDS 52160B -> 3 blocks/CU -> 12 waves/CU (residency 4-16 proven
// irrelevant by R7). This kernel removes BOTH serial components:
//  (a) L1 transactions: staged inputs, LDS dep tables, LDS frames,
//      transposed coalesced outR stores;
//  (b) VALU cndmask storm: atoms read frames from LDS (frow) instead of
//      the 84-cndmask sel8 gather (24x/residue).
#define TDEP_I 0
#define RDEP_I 198
#define WREG_F 752
#define WREG_STRIDE 3072
#define SMEM_BYTES ((WREG_F + 4 * WREG_STRIDE) * 4)   // 52160 B -> 3 blocks/CU

// sel8 kept ONLY for the 7-step dependency chain (7x84 cndmasks).
__device__ __forceinline__ void sel8(const float (&fr)[8][12], int d, float (&P)[12]) {
    const bool b0 = (d & 1) != 0;
    const bool b1 = (d & 2) != 0;
    const bool b2 = (d & 4) != 0;
#pragma unroll
    for (int k = 0; k < 12; ++k) {
        float a01 = b0 ? fr[1][k] : fr[0][k];
        float a23 = b0 ? fr[3][k] : fr[2][k];
        float a45 = b0 ? fr[5][k] : fr[4][k];
        float a67 = b0 ? fr[7][k] : fr[6][k];
        float b03 = b1 ? a23 : a01;
        float b47 = b1 ? a67 : a45;
        P[k] = b2 ? b47 : b03;
    }
}

// Read frame row j of frame d from slot s (XOR-swizzled layout).
__device__ __forceinline__ float4 frow(const float4* fbase, int s, int d, int j) {
    int x = 3 * d + j;
    int xs = (x & 24) | ((x ^ s) & 7);
    return fbase[xs];
}

__device__ __forceinline__ float ap(float4 r, float x, float y, float z) {
    return fmaf(r.x, x, fmaf(r.y, y, fmaf(r.z, z, r.w)));
}

// Wave-local coalesced global->LDS staging (src 16B-aligned at wave granularity).
__device__ __forceinline__ void wave_stage(const float* __restrict__ src, float* dst,
                                           int nF, int lane) {
    const int n4 = nF >> 2;
    const float4* s4 = (const float4*)src;
    float4* d4 = (float4*)dst;
    for (int i = lane; i < n4; i += 64) d4[i] = s4[i];
    const int rem = nF & 3;
    if (lane < rem) {
        const int b = n4 << 2;
        dst[b + lane] = src[b + lane];
    }
}

#define LGKM0() asm volatile("s_waitcnt lgkmcnt(0)" ::: "memory")

extern "C" __global__ __launch_bounds__(256)
void model_kernel(const float* __restrict__ o0,     // (N,17)
                  const float* __restrict__ o1,     // (N,3,3)
                  const float* __restrict__ pos,    // (N,3)
                  const int*   __restrict__ ssArr,  // (N,)
                  const int*   __restrict__ rtArr,  // (N,)
                  const float* __restrict__ rigT,   // (3,22,8,4,3)
                  const float* __restrict__ rigG,   // (3,22,24,3)
                  const int*   __restrict__ tdepArr,// (22,8)
                  const int*   __restrict__ rdepArr,// (22,24)
                  float* __restrict__ outR,         // (N,24,3)
                  float* __restrict__ outF,         // (N,4,3)
                  int N)
{
    extern __shared__ __align__(16) float smem[];
    int* smemI = (int*)smem;
    const int tid  = threadIdx.x;
    const int lane = tid & 63;
    const int wave = tid >> 6;

    // ---- stage dep tables (tiny) ----
    for (int t = tid; t < 176; t += 256)
        smemI[TDEP_I + (t >> 3) * 9 + (t & 7)] = tdepArr[t];
    for (int t = tid; t < 528; t += 256) {
        int r = t / 24;
        smemI[RDEP_I + r * 25 + (t - r * 24)] = rdepArr[t];
    }
    __syncthreads();

    float*  wreg  = smem + WREG_F + wave * WREG_STRIDE;
    float4* wreg4 = (float4*)wreg;
    const int gstride = (int)gridDim.x * 256;

    for (int base = (int)blockIdx.x * 256; base < N; base += gstride) {
        const int wres0 = base + wave * 64;
        const int cnt   = min(64, N - wres0);

        LGKM0();   // WAR vs previous iteration's LDS reads (wave-local reuse)
        if (cnt > 0) {
            wave_stage(o0  + (size_t)wres0 * 17, wreg,        cnt * 17, lane);
            wave_stage(o1  + (size_t)wres0 * 9,  wreg + 1088, cnt * 9,  lane);
            wave_stage(pos + (size_t)wres0 * 3,  wreg + 1664, cnt * 3,  lane);
        }
        LGKM0();   // staged inputs visible (cross-lane, wave-synchronous)

        const int  res   = wres0 + lane;
        const bool alive = (lane < cnt);

        float fr[8][12];

        if (alive) {
            const int s    = ssArr[res];
            const int rt   = rtArr[res];
            const int sr22 = s * NRES + rt;

            // ---- torsion cos/sin from LDS (stride 17, odd) ----
            const float* myo0 = wreg + lane * 17;
            float c[7], sn[7];
#pragma unroll
            for (int t = 0; t < 7; ++t) {
                float cr = myo0[2 * t], sr = myo0[2 * t + 1];
                float inv = rsqrtf(fmaxf(cr * cr + sr * sr, 1e-12f));
                c[t]  = cr * inv;
                sn[t] = sr * inv;
            }

            // ---- backbone frame (Gram-Schmidt) ----
            const float* myo1 = wreg + 1088 + lane * 9;
            float r0x = myo1[0], r0y = myo1[1], r0z = myo1[2];
            float v1x = myo1[3], v1y = myo1[4], v1z = myo1[5];
            float t2x = myo1[6], t2y = myo1[7], t2z = myo1[8];
            float inv0 = rsqrtf(fmaxf(r0x * r0x + r0y * r0y + r0z * r0z, 1e-12f));
            float e0x = r0x * inv0, e0y = r0y * inv0, e0z = r0z * inv0;
            float d01 = e0x * v1x + e0y * v1y + e0z * v1z;
            float u1x = v1x - e0x * d01, u1y = v1y - e0y * d01, u1z = v1z - e0z * d01;
            float inv1 = rsqrtf(fmaxf(u1x * u1x + u1y * u1y + u1z * u1z, 1e-12f));
            float e1x = u1x * inv1, e1y = u1y * inv1, e1z = u1z * inv1;
            float e2x = e0y * e1z - e0z * e1y;
            float e2y = e0z * e1x - e0x * e1z;
            float e2z = e0x * e1y - e0y * e1x;
            const float* myp = wreg + 1664 + lane * 3;
            float btx = 0.1f * t2x + myp[0];
            float bty = 0.1f * t2y + myp[1];
            float btz = 0.1f * t2z + myp[2];

            // ---- frames from global rigT (66-record table, L1/L2-hot) ----
            const float4* T4 = (const float4*)rigT + (size_t)sr22 * 24;

            {   // frame 0 = combine(T0, [rot(cols e0,e1,e2); bt])
                float4 q0 = T4[0], q1 = T4[1], q2 = T4[2];
                float T0[12] = {q0.x, q0.y, q0.z, q0.w, q1.x, q1.y, q1.z, q1.w,
                                q2.x, q2.y, q2.z, q2.w};
#pragma unroll
                for (int i = 0; i < 3; ++i) {
                    float a = T0[i * 3 + 0], b = T0[i * 3 + 1], d = T0[i * 3 + 2];
                    fr[0][i * 3 + 0] = a * e0x + b * e0y + d * e0z;
                    fr[0][i * 3 + 1] = a * e1x + b * e1y + d * e1z;
                    fr[0][i * 3 + 2] = a * e2x + b * e2y + d * e2z;
                    fr[0][9 + i]     = a * btx + b * bty + d * btz + T0[9 + i];
                }
            }
#pragma unroll
            for (int f = 1; f < 8; ++f) {   // combine(Tf, rotX(c,s))
                float4 q0 = T4[f * 3 + 0], q1 = T4[f * 3 + 1], q2 = T4[f * 3 + 2];
                float Tf[12] = {q0.x, q0.y, q0.z, q0.w, q1.x, q1.y, q1.z, q1.w,
                                q2.x, q2.y, q2.z, q2.w};
                float cc = c[f - 1], ssn = sn[f - 1];
#pragma unroll
                for (int i = 0; i < 3; ++i) {
                    fr[f][i * 3 + 0] = Tf[i * 3 + 0];
                    fr[f][i * 3 + 1] = Tf[i * 3 + 1] * cc + Tf[i * 3 + 2] * ssn;
                    fr[f][i * 3 + 2] = Tf[i * 3 + 2] * cc - Tf[i * 3 + 1] * ssn;
                    fr[f][9 + i]     = Tf[9 + i];
                }
            }

            // ---- sequential dependency chain (sel8 here only: 7x84) ----
            const int* tdp = smemI + TDEP_I + rt * 9;
#pragma unroll
            for (int i = 1; i < 8; ++i) {
                float P[12];
                sel8(fr, tdp[i] & 7, P);
                float Y[12];
#pragma unroll
                for (int k = 0; k < 12; ++k) Y[k] = fr[i][k];
#pragma unroll
                for (int r = 0; r < 3; ++r) {
                    float a = P[r * 3 + 0], b = P[r * 3 + 1], d = P[r * 3 + 2];
#pragma unroll
                    for (int j = 0; j < 3; ++j)
                        fr[i][r * 3 + j] = a * Y[j] + b * Y[3 + j] + d * Y[6 + j];
                    fr[i][9 + r] = a * Y[9] + b * Y[10] + d * Y[11] + P[9 + r];
                }
            }

            // ---- second output: opr[:,0] (aligned float4, direct) ----
            float4* OF4 = (float4*)outF + (size_t)res * 3;
            OF4[0] = make_float4(fr[0][0], fr[0][1], fr[0][2], fr[0][3]);
            OF4[1] = make_float4(fr[0][4], fr[0][5], fr[0][6], fr[0][7]);
            OF4[2] = make_float4(fr[0][8], fr[0][9], fr[0][10], fr[0][11]);
        }

        // ==== atoms in two 32-residue sub-batches, 2 lanes per residue ====
#pragma unroll 1
        for (int b = 0; b < 2; ++b) {
            const int sb0  = wres0 + 32 * b;
            const int scnt = min(32, cnt - 32 * b);
            if (scnt <= 0) break;                 // wave-uniform

            const int  s32    = lane & 31;
            const int  half   = lane >> 5;
            const bool aalive = (s32 < scnt);

            // issue per-lane table gathers EARLY (latency hides under frame writes)
            int rtp = 0, sr22p = 0;
            float4 g[9];
            if (aalive) {
                const int resp = sb0 + s32;
                rtp   = rtArr[resp];
                sr22p = ssArr[resp] * NRES + rtp;
                const float4* G4 = (const float4*)rigG + (size_t)sr22p * 18 + half * 9;
#pragma unroll
                for (int j = 0; j < 9; ++j) g[j] = G4[j];
            }

            LGKM0();   // WAR: prior phase's LDS reads done before frame writes
            // owner lanes of this sub-batch dump their 8 frames (rows as [a b c t])
            if (half == b && s32 < scnt) {
                float4* fp = wreg4 + s32 * 24;
#pragma unroll
                for (int f = 0; f < 8; ++f)
#pragma unroll
                    for (int j = 0; j < 3; ++j) {
                        int x  = f * 3 + j;
                        int xs = (x & 24) | ((x ^ s32) & 7);
                        fp[xs] = make_float4(fr[f][3 * j], fr[f][3 * j + 1],
                                             fr[f][3 * j + 2], fr[f][9 + j]);
                    }
            }
            LGKM0();   // frames visible (cross-lane, wave-synchronous)

            float4 outv[9];
            if (aalive) {
                const int*    rdp   = smemI + RDEP_I + rtp * 25 + half * 12;
                const float4* fbase = wreg4 + s32 * 24;
#pragma unroll
                for (int ck = 0; ck < 3; ++ck) {
                    int d0 = rdp[ck * 4 + 0] & 7, d1 = rdp[ck * 4 + 1] & 7;
                    int d2 = rdp[ck * 4 + 2] & 7, d3 = rdp[ck * 4 + 3] & 7;
                    float4 g0 = g[ck * 3 + 0], g1 = g[ck * 3 + 1], g2 = g[ck * 3 + 2];
                    float4 r0, r1, r2;
                    float p0x, p0y, p0z, p1x, p1y, p1z, p2x, p2y, p2z, p3x, p3y, p3z;
                    r0 = frow(fbase, s32, d0, 0); r1 = frow(fbase, s32, d0, 1); r2 = frow(fbase, s32, d0, 2);
                    p0x = ap(r0, g0.x, g0.y, g0.z); p0y = ap(r1, g0.x, g0.y, g0.z); p0z = ap(r2, g0.x, g0.y, g0.z);
                    r0 = frow(fbase, s32, d1, 0); r1 = frow(fbase, s32, d1, 1); r2 = frow(fbase, s32, d1, 2);
                    p1x = ap(r0, g0.w, g1.x, g1.y); p1y = ap(r1, g0.w, g1.x, g1.y); p1z = ap(r2, g0.w, g1.x, g1.y);
                    r0 = frow(fbase, s32, d2, 0); r1 = frow(fbase, s32, d2, 1); r2 = frow(fbase, s32, d2, 2);
                    p2x = ap(r0, g1.z, g1.w, g2.x); p2y = ap(r1, g1.z, g1.w, g2.x); p2z = ap(r2, g1.z, g1.w, g2.x);
                    r0 = frow(fbase, s32, d3, 0); r1 = frow(fbase, s32, d3, 1); r2 = frow(fbase, s32, d3, 2);
                    p3x = ap(r0, g2.y, g2.z, g2.w); p3y = ap(r1, g2.y, g2.z, g2.w); p3z = ap(r2, g2.y, g2.z, g2.w);
                    outv[ck * 3 + 0] = make_float4(p0x, p0y, p0z, p1x);
                    outv[ck * 3 + 1] = make_float4(p1y, p1z, p2x, p2y);
                    outv[ck * 3 + 2] = make_float4(p2z, p3x, p3y, p3z);
                }
            }

            LGKM0();   // WAR: frame reads done before transpose writes clobber them
            if (aalive) {
                float4* hp = wreg4 + (s32 * 2 + half) * 11;   // stride 11: quartets swept
#pragma unroll
                for (int j = 0; j < 9; ++j) hp[j] = outv[j];
            }
            LGKM0();   // transpose visible

            {   // coalesced float4 stores of scnt*72 contiguous floats
                float4*   dst = (float4*)outR + (size_t)sb0 * 18;
                const int n4  = scnt * 18;
                for (int i = lane; i < n4; i += 64) {
                    int h = i / 9;                 // const-div -> magic mul
                    dst[i] = wreg4[h * 11 + (i - h * 9)];
                }
            }
        }
    }
}

extern "C" void kernel_launch(void* const* d_in, const int* in_sizes, int n_in,
                              void* d_out, int out_size, void* d_ws, size_t ws_size,
                              hipStream_t stream) {
    const float* o0   = (const float*)d_in[0];
    const float* o1   = (const float*)d_in[1];
    const float* pos  = (const float*)d_in[2];
    const int*   ssA  = (const int*)d_in[3];
    const int*   rtA  = (const int*)d_in[4];
    const float* rigT = (const float*)d_in[5];
    const float* rigG = (const float*)d_in[6];
    const int*   tdep = (const int*)d_in[7];
    const int*   rdep = (const int*)d_in[8];

    const int N = in_sizes[3]; // ss has N elements
    float* outR = (float*)d_out;
    float* outF = (float*)d_out + (size_t)N * 72;

    static bool attr_set = false;
    if (!attr_set) {
        hipFuncSetAttribute((const void*)model_kernel,
                            hipFuncAttributeMaxDynamicSharedMemorySize, SMEM_BYTES);
        attr_set = true;
    }

    int grid = (N + 255) / 256;
    if (grid > 768) grid = 768;   // persistent; LDS 52160B -> 3 blocks/CU
    model_kernel<<<grid, 256, SMEM_BYTES, stream>>>(o0, o1, pos, ssA, rtA, rigT, rigG,
                                                    tdep, rdep, outR, outF, N);
}

// Round 9
// 185.255 us; speedup vs baseline: 1.1410x; 1.1410x over previous
//
#include <hip/hip_runtime.h>
#include <math.h>

#define NRES 22

// R0 body (proven VGPR~92-104, no spills, FETCH/WRITE ~= ideal) with the 42
// table-gather instructions per wave-iter redirected from GLOBAL to LDS.
// Theory: 44KB rigT/rigG don't fit 32KB L1; streaming loads/stores evict
// table lines continuously -> every gather goes to L2, saturating per-CU
// miss handling (shared!), which is why extra waves (R7: 16/CU) made things
// WORSE, not better. R1 (tables in LDS) is the session best at 77us but was
// pinned to 2 blocks/CU by 79KB LDS. This round: tables-ONLY in LDS
// (49,456B -> 3 blocks/CU = 12 waves/CU), direct input loads, direct
// stores, NO fences (tables are read-only after one __syncthreads).
//   sT : rigT 66 rec x 100 floats (pad: b128 quartet spread)   [0..26400B)
//   sG : rigG 66 rec x 76 floats                               [26400..46464B)
//   sTd: tdep 22x9 ints ; sRd: rdep 22x25 ints                 [46464..49456B)
#define ST_F    0
#define SG_F    6600
#define STD_I   11616
#define SRD_I   11814
#define TBL_F   12364
#define SMEM_BYTES (TBL_F * 4)   // 49456 B -> 3 blocks/CU

// Select fr[d] (d in 0..7) into P via a 3-level cndmask tree.
__device__ __forceinline__ void sel8(const float (&fr)[8][12], int d, float (&P)[12]) {
    const bool b0 = (d & 1) != 0;
    const bool b1 = (d & 2) != 0;
    const bool b2 = (d & 4) != 0;
#pragma unroll
    for (int k = 0; k < 12; ++k) {
        float a01 = b0 ? fr[1][k] : fr[0][k];
        float a23 = b0 ? fr[3][k] : fr[2][k];
        float a45 = b0 ? fr[5][k] : fr[4][k];
        float a67 = b0 ? fr[7][k] : fr[6][k];
        float b03 = b1 ? a23 : a01;
        float b47 = b1 ? a67 : a45;
        P[k] = b2 ? b47 : b03;
    }
}

__device__ __forceinline__ void apply_point(const float (&F)[12], float x, float y, float z,
                                            float &px, float &py, float &pz) {
    px = fmaf(F[0], x, fmaf(F[1], y, fmaf(F[2], z, F[9])));
    py = fmaf(F[3], x, fmaf(F[4], y, fmaf(F[5], z, F[10])));
    pz = fmaf(F[6], x, fmaf(F[7], y, fmaf(F[8], z, F[11])));
}

extern "C" __global__ __launch_bounds__(256)
void model_kernel(const float* __restrict__ o0,     // (N,17)
                  const float* __restrict__ o1,     // (N,3,3)
                  const float* __restrict__ pos,    // (N,3)
                  const int*   __restrict__ ssArr,  // (N,)
                  const int*   __restrict__ rtArr,  // (N,)
                  const float* __restrict__ rigT,   // (3,22,8,4,3)
                  const float* __restrict__ rigG,   // (3,22,24,3)
                  const int*   __restrict__ tdepArr,// (22,8)
                  const int*   __restrict__ rdepArr,// (22,24)
                  float* __restrict__ outR,         // (N,24,3)
                  float* __restrict__ outF,         // (N,4,3)
                  int N)
{
    extern __shared__ __align__(16) float smem[];
    int* smemI = (int*)smem;
    const int tid = threadIdx.x;

    // ---- stage tables into LDS once (coalesced reads, padded writes) ----
    {
        const float4* s4 = (const float4*)rigT;        // 6336 floats = 1584 float4
        for (int t = tid; t < 1584; t += 256) {
            float4 v = s4[t];
            int rec = t / 24;
            int k   = (t - rec * 24) << 2;             // multiple of 4 -> b128 aligned
            *(float4*)(smem + ST_F + rec * 100 + k) = v;
        }
    }
    {
        const float4* s4 = (const float4*)rigG;        // 4752 floats = 1188 float4
        for (int t = tid; t < 1188; t += 256) {
            float4 v = s4[t];
            int rec = t / 18;
            int k   = (t - rec * 18) << 2;
            *(float4*)(smem + SG_F + rec * 76 + k) = v;
        }
    }
    for (int t = tid; t < 176; t += 256)
        smemI[STD_I + (t >> 3) * 9 + (t & 7)] = tdepArr[t];
    for (int t = tid; t < 528; t += 256) {
        int r = t / 24;
        smemI[SRD_I + r * 25 + (t - r * 24)] = rdepArr[t];
    }
    __syncthreads();   // tables read-only from here on; no further sync needed

    const int tid0    = (int)blockIdx.x * 256 + tid;
    const int gstride = (int)gridDim.x * 256;

    for (int res = tid0; res < N; res += gstride) {
        const int s  = ssArr[res];
        const int rt = rtArr[res];

        // ---- torsion cos/sin (normalize pairs), direct global loads ----
        float c[7], sn[7];
        const float* o0p = o0 + (size_t)res * 17;
#pragma unroll
        for (int t = 0; t < 7; ++t) {
            float cr = o0p[2 * t], sr = o0p[2 * t + 1];
            float inv = rsqrtf(fmaxf(cr * cr + sr * sr, 1e-12f));
            c[t]  = cr * inv;
            sn[t] = sr * inv;
        }

        // ---- backbone frame (Gram-Schmidt) ----
        const float* o1p = o1 + (size_t)res * 9;
        float r0x = o1p[0], r0y = o1p[1], r0z = o1p[2];
        float v1x = o1p[3], v1y = o1p[4], v1z = o1p[5];
        float t2x = o1p[6], t2y = o1p[7], t2z = o1p[8];
        float inv0 = rsqrtf(fmaxf(r0x * r0x + r0y * r0y + r0z * r0z, 1e-12f));
        float e0x = r0x * inv0, e0y = r0y * inv0, e0z = r0z * inv0;
        float d01 = e0x * v1x + e0y * v1y + e0z * v1z;
        float u1x = v1x - e0x * d01, u1y = v1y - e0y * d01, u1z = v1z - e0z * d01;
        float inv1 = rsqrtf(fmaxf(u1x * u1x + u1y * u1y + u1z * u1z, 1e-12f));
        float e1x = u1x * inv1, e1y = u1y * inv1, e1z = u1z * inv1;
        float e2x = e0y * e1z - e0z * e1y;
        float e2y = e0z * e1x - e0x * e1z;
        float e2z = e0x * e1y - e0y * e1x;
        const float* pp = pos + (size_t)res * 3;
        float btx = 0.1f * t2x + pp[0];
        float bty = 0.1f * t2y + pp[1];
        float btz = 0.1f * t2z + pp[2];

        const int sr22 = s * NRES + rt;
        // ---- frames from LDS rigT (record = sr22*25 float4) ----
        const float4* T4 = (const float4*)smem + sr22 * 25;

        float fr[8][12];

        // frame 0 = combine(T0, [rot(cols e0,e1,e2); bt])
        {
            float4 q0 = T4[0], q1 = T4[1], q2 = T4[2];
            float T0[12] = {q0.x, q0.y, q0.z, q0.w, q1.x, q1.y, q1.z, q1.w,
                            q2.x, q2.y, q2.z, q2.w};
#pragma unroll
            for (int i = 0; i < 3; ++i) {
                float a = T0[i * 3 + 0], b = T0[i * 3 + 1], d = T0[i * 3 + 2];
                fr[0][i * 3 + 0] = a * e0x + b * e0y + d * e0z;
                fr[0][i * 3 + 1] = a * e1x + b * e1y + d * e1z;
                fr[0][i * 3 + 2] = a * e2x + b * e2y + d * e2z;
                fr[0][9 + i]     = a * btx + b * bty + d * btz + T0[9 + i];
            }
        }

        // frames 1..7 = combine(Tf, rotX(c,s))
#pragma unroll
        for (int f = 1; f < 8; ++f) {
            float4 q0 = T4[f * 3 + 0], q1 = T4[f * 3 + 1], q2 = T4[f * 3 + 2];
            float Tf[12] = {q0.x, q0.y, q0.z, q0.w, q1.x, q1.y, q1.z, q1.w,
                            q2.x, q2.y, q2.z, q2.w};
            float cc = c[f - 1], ssn = sn[f - 1];
#pragma unroll
            for (int i = 0; i < 3; ++i) {
                fr[f][i * 3 + 0] = Tf[i * 3 + 0];
                fr[f][i * 3 + 1] = Tf[i * 3 + 1] * cc + Tf[i * 3 + 2] * ssn;
                fr[f][i * 3 + 2] = Tf[i * 3 + 2] * cc - Tf[i * 3 + 1] * ssn;
                fr[f][9 + i]     = Tf[9 + i];
            }
        }

        // ---- sequential dependency chain (tdep from LDS, stride 9 odd) ----
        const int* tdp = smemI + STD_I + rt * 9;
#pragma unroll
        for (int i = 1; i < 8; ++i) {
            float P[12];
            sel8(fr, tdp[i] & 7, P);
            float Y[12];
#pragma unroll
            for (int k = 0; k < 12; ++k) Y[k] = fr[i][k];
#pragma unroll
            for (int r = 0; r < 3; ++r) {
                float a = P[r * 3 + 0], b = P[r * 3 + 1], d = P[r * 3 + 2];
#pragma unroll
                for (int j = 0; j < 3; ++j)
                    fr[i][r * 3 + j] = a * Y[j] + b * Y[3 + j] + d * Y[6 + j];
                fr[i][9 + r] = a * Y[9] + b * Y[10] + d * Y[11] + P[9 + r];
            }
        }

        // ---- atoms: rigG/rdep from LDS, direct float4 stores (R0-proven) ----
        const float4* G4  = (const float4*)smem + 1650 + sr22 * 19;   // SG_F/4 + rec*19
        const int*    rdp = smemI + SRD_I + rt * 25;
        float4* OR4 = (float4*)(outR + (size_t)res * 72);
#pragma unroll
        for (int ck = 0; ck < 6; ++ck) {
            int d0 = rdp[ck * 4 + 0] & 7, d1 = rdp[ck * 4 + 1] & 7;
            int d2 = rdp[ck * 4 + 2] & 7, d3 = rdp[ck * 4 + 3] & 7;
            float4 g0 = G4[ck * 3 + 0], g1 = G4[ck * 3 + 1], g2 = G4[ck * 3 + 2];
            float P[12];
            float p0x, p0y, p0z, p1x, p1y, p1z, p2x, p2y, p2z, p3x, p3y, p3z;
            sel8(fr, d0, P); apply_point(P, g0.x, g0.y, g0.z, p0x, p0y, p0z);
            sel8(fr, d1, P); apply_point(P, g0.w, g1.x, g1.y, p1x, p1y, p1z);
            sel8(fr, d2, P); apply_point(P, g1.z, g1.w, g2.x, p2x, p2y, p2z);
            sel8(fr, d3, P); apply_point(P, g2.y, g2.z, g2.w, p3x, p3y, p3z);
            OR4[ck * 3 + 0] = make_float4(p0x, p0y, p0z, p1x);
            OR4[ck * 3 + 1] = make_float4(p1y, p1z, p2x, p2y);
            OR4[ck * 3 + 2] = make_float4(p2z, p3x, p3y, p3z);
        }

        // ---- second output: opr[:,0] ----
        float4* OF4 = (float4*)(outF + (size_t)res * 12);
        OF4[0] = make_float4(fr[0][0], fr[0][1], fr[0][2], fr[0][3]);
        OF4[1] = make_float4(fr[0][4], fr[0][5], fr[0][6], fr[0][7]);
        OF4[2] = make_float4(fr[0][8], fr[0][9], fr[0][10], fr[0][11]);
    }
}

extern "C" void kernel_launch(void* const* d_in, const int* in_sizes, int n_in,
                              void* d_out, int out_size, void* d_ws, size_t ws_size,
                              hipStream_t stream) {
    const float* o0   = (const float*)d_in[0];
    const float* o1   = (const float*)d_in[1];
    const float* pos  = (const float*)d_in[2];
    const int*   ssA  = (const int*)d_in[3];
    const int*   rtA  = (const int*)d_in[4];
    const float* rigT = (const float*)d_in[5];
    const float* rigG = (const float*)d_in[6];
    const int*   tdep = (const int*)d_in[7];
    const int*   rdep = (const int*)d_in[8];

    const int N = in_sizes[3]; // ss has N elements
    float* outR = (float*)d_out;
    float* outF = (float*)d_out + (size_t)N * 72;

    static bool attr_set = false;
    if (!attr_set) {
        hipFuncSetAttribute((const void*)model_kernel,
                            hipFuncAttributeMaxDynamicSharedMemorySize, SMEM_BYTES);
        attr_set = true;
    }

    // Persistent: 768 WGs x 256 thd; LDS 49,456B -> 3 blocks/CU = 12 waves/CU.
    int grid = (N + 255) / 256;
    if (grid > 768) grid = 768;
    model_kernel<<<grid, 256, SMEM_BYTES, stream>>>(o0, o1, pos, ssA, rtA, rigT, rigG,
                                                    tdep, rdep, outR, outF, N);
}